// Round 3
// baseline (426.666 us; speedup 1.0000x reference)
//
#include <hip/hip_runtime.h>

// TensorConvolutionTrainLayer: S=512,P=196,Q=48,CB=8,R=32,C=10,N=8
// R3: latency-focused rework of the fused chain:
//  - Mt stored s-major [s][row 8..392 -> 384][232] so per-(s,step) A slice is one
//    contiguous 29.7KB burst; first/last rows go to MtF/MtL (old layout) for the
//    small state0/GN GEMMs.
//  - B fragments for cc+1 prefetched into VGPRs before cc's contraction (VALU
//    covers L2 latency; no vmcnt(0) inside the cc loop).
//  - Next step's A staged during the reduce phase.
//  - Contraction in float2 (v_pk_fma_f32).

typedef _Float16 half8 __attribute__((ext_vector_type(8)));
typedef float floatx4 __attribute__((ext_vector_type(4)));

#define KP 224    // P=196 padded to 7*32
#define QP 64     // Q=48 padded to 2*32
#define NROWS 400 // 8 first + 6*64 mid + 8 last
#define LDA2 232  // Mt2 row stride (halfs): 224 + 8 pad -> 29x16B chunks, bank-friendly

__device__ __forceinline__ void gld_lds16(const void* g, void* l) {
  __builtin_amdgcn_global_load_lds((const __attribute__((address_space(1))) void*)g,
                                   (__attribute__((address_space(3))) void*)l, 16, 0, 0);
}

// ---------------- generic MFMA GEMM ----------------
// A: [M][K] f16 row-major, Bt: [N][K] f16 row-major. 128x128 tile, 4 waves.
// MODE0 epilogue splits rows across Mt2 (s-major, stride 232) / MtF / MtL.
template<int K, int MODE>
__global__ __launch_bounds__(256)
void gemm_mfma(const _Float16* __restrict__ A, const _Float16* __restrict__ Bt,
               void* __restrict__ out0, void* __restrict__ out1, void* __restrict__ out2)
{
  __shared__ __align__(16) _Float16 Ash[128 * 32];
  __shared__ __align__(16) _Float16 Bsh[128 * 32];
  const int tid  = threadIdx.x;
  const int wave = tid >> 6;
  const int lane = tid & 63;
  const int m0 = blockIdx.y * 128;
  const int n0 = blockIdx.x * 128;
  const int wm = (wave >> 1) * 64;
  const int wn = (wave & 1) * 64;
  const int fr = lane & 15;
  const int fq = lane >> 4;

  floatx4 acc[4][4] = {};

  for (int kt = 0; kt < K; kt += 32) {
    __syncthreads();
#pragma unroll
    for (int j = 0; j < 2; j++) {
      const int c   = j * 256 + tid;
      const int row = c >> 2;
      const int ko  = (c & 3) * 8;
      gld_lds16(A  + (size_t)(m0 + row) * K + kt + ko,
                (char*)Ash + (size_t)(j * 256 + wave * 64) * 16);
      gld_lds16(Bt + (size_t)(n0 + row) * K + kt + ko,
                (char*)Bsh + (size_t)(j * 256 + wave * 64) * 16);
    }
    __syncthreads();
    half8 af[4], bf[4];
#pragma unroll
    for (int i = 0; i < 4; i++)
      af[i] = *(const half8*)&Ash[(wm + i * 16 + fr) * 32 + fq * 8];
#pragma unroll
    for (int i = 0; i < 4; i++)
      bf[i] = *(const half8*)&Bsh[(wn + i * 16 + fr) * 32 + fq * 8];
#pragma unroll
    for (int i = 0; i < 4; i++)
#pragma unroll
      for (int j = 0; j < 4; j++)
        acc[i][j] = __builtin_amdgcn_mfma_f32_16x16x32_f16(af[i], bf[j], acc[i][j], 0, 0, 0);
  }

  // C/D layout: col = lane&15, row = quad*4 + reg  [measured m89/m91]
#pragma unroll
  for (int i = 0; i < 4; i++) {
#pragma unroll
    for (int j = 0; j < 4; j++) {
#pragma unroll
      for (int r = 0; r < 4; r++) {
        const int m = m0 + wm + i * 16 + fq * 4 + r;
        const int n = n0 + wn + j * 16 + fr;
        const float v = acc[i][j][r];
        if constexpr (MODE == 0) {
          // n = s*196 + p
          const unsigned s = (unsigned)n / 196u;
          const unsigned p = (unsigned)n - s * 196u;
          if (m < 8)            // -> MtF[b=m][s][224]
            ((_Float16*)out1)[((size_t)m * 512 + s) * KP + p] = (_Float16)v;
          else if (m < 392)     // -> Mt2[s][m-8][232]
            ((_Float16*)out0)[((size_t)s * 384 + (m - 8)) * LDA2 + p] = (_Float16)v;
          else if (m < NROWS)   // -> MtL[a=m-392][s][224]
            ((_Float16*)out2)[((size_t)(m - 392) * 512 + s) * KP + p] = (_Float16)v;
        } else if constexpr (MODE == 2) {
          // state0: m = b*512+s, n = r*10+c -> St0[s][b*320 + n]
          if (n < 320)
            ((float*)out0)[(size_t)(m & 511) * 2560 + (m >> 9) * 320 + n] = v;
        } else {
          // GN: m = a*512+s, n = l -> GN[(a*512+s)*32 + l]
          if (n < 32)
            ((float*)out0)[(size_t)m * 32 + n] = v;
        }
      }
    }
  }
}

// ---------------- fused chain kernel ----------------
__device__ __forceinline__ void stageA(const _Float16* __restrict__ base,
                                       _Float16* __restrict__ ash, int tid) {
  const int wave = tid >> 6;
#pragma unroll
  for (int it = 0; it < 7; it++) {
    const int c = it * 256 + tid;
    gld_lds16(base + (size_t)c * 8, (char*)ash + (size_t)(it * 256 + wave * 64) * 16);
  }
  if (tid < 64)  // chunks 1792..1855 (wave-uniform branch)
    gld_lds16(base + (size_t)(1792 + tid) * 8, (char*)ash + (size_t)1792 * 16);
}

__global__ __launch_bounds__(256, 2)
void chain_kernel(const _Float16* __restrict__ Mt2, const _Float16* __restrict__ Akr,
                  const float* __restrict__ St0, const float* __restrict__ GN,
                  float* __restrict__ out)
{
  __shared__ __align__(16) _Float16 Ash[64 * LDA2];     // 29696 B
  __shared__ __align__(16) float St[8 * 32 * 12];       // 12288 B (c padded 10->12)
  __shared__ __align__(16) float NSp[2][8 * 32 * 10];   // 20480 B
  __shared__ float oc[10];

  const int tid  = threadIdx.x;
  const int wave = tid >> 6;
  const int lane = tid & 63;
  const int s    = blockIdx.x;
  const int fr   = lane & 15;
  const int fq   = lane >> 4;
  const int fqh  = fq >> 1;       // a parity bit
  const int fql  = fq & 1;        // b high bit

  // initial state: St0[s][tid*10 + c] -> St[tid*12 + c]
  {
    const float* src = St0 + (size_t)s * 2560 + tid * 10;
    float* dst = &St[tid * 12];
#pragma unroll
    for (int c = 0; c < 10; c += 2) *(float2*)&dst[c] = *(const float2*)&src[c];
    if (tid < 10) oc[tid] = 0.f;
  }
  stageA(Mt2 + (size_t)s * 384 * LDA2, Ash, tid);   // step 0 A slice

  for (int k = 0; k < 6; k++) {
    __syncthreads();  // Ash staged (vmcnt drained by barrier), St ready

    float2 ns[2][4][5];
#pragma unroll
    for (int ni = 0; ni < 2; ni++)
#pragma unroll
      for (int rg = 0; rg < 4; rg++)
#pragma unroll
        for (int j = 0; j < 5; j++) ns[ni][rg][j] = make_float2(0.f, 0.f);

    const _Float16* Bk = Akr + (size_t)k * 1024 * KP;
    // preload cc=0 B fragments (14 x dwordx4)
    half8 bf[7][2];
    {
      const _Float16* Bb = Bk + (size_t)(wave * 32) * KP;
#pragma unroll
      for (int kt = 0; kt < 7; kt++)
#pragma unroll
        for (int ni = 0; ni < 2; ni++)
          bf[kt][ni] = *(const half8*)(Bb + (size_t)(ni * 16 + fr) * KP + kt * 32 + fq * 8);
    }

    for (int cc = 0; cc < 8; cc++) {
      floatx4 acc[4][2] = {};
#pragma unroll
      for (int kt = 0; kt < 7; kt++) {
        half8 af[4];
#pragma unroll
        for (int mi = 0; mi < 4; mi++)
          af[mi] = *(const half8*)&Ash[(mi * 16 + fr) * LDA2 + kt * 32 + fq * 8];
#pragma unroll
        for (int mi = 0; mi < 4; mi++)
#pragma unroll
          for (int ni = 0; ni < 2; ni++)
            acc[mi][ni] = __builtin_amdgcn_mfma_f32_16x16x32_f16(af[mi], bf[kt][ni], acc[mi][ni], 0, 0, 0);
      }
      // prefetch cc+1 B fragments; the contraction below covers their L2 latency
      if (cc < 7) {
        const _Float16* Bn = Bk + (size_t)((cc + 1) * 128 + wave * 32) * KP;
#pragma unroll
        for (int kt = 0; kt < 7; kt++)
#pragma unroll
          for (int ni = 0; ni < 2; ni++)
            bf[kt][ni] = *(const half8*)(Bn + (size_t)(ni * 16 + fr) * KP + kt * 32 + fq * 8);
      }
      // contract G (regs) with St (LDS): l = cc*4 + wave
      const int l = cc * 4 + wave;
#pragma unroll
      for (int mi = 0; mi < 4; mi++) {
        const float* stp = &St[(2 * mi + fqh) * 384 + l * 12];
        const floatx4 s0 = *(const floatx4*)stp;
        const floatx4 s1 = *(const floatx4*)(stp + 4);
        const float2  s2 = *(const float2*)(stp + 8);
        float2 stv[5] = {make_float2(s0[0], s0[1]), make_float2(s0[2], s0[3]),
                         make_float2(s1[0], s1[1]), make_float2(s1[2], s1[3]), s2};
#pragma unroll
        for (int ni = 0; ni < 2; ni++)
#pragma unroll
          for (int rg = 0; rg < 4; rg++) {
            const float g = acc[mi][ni][rg];
#pragma unroll
            for (int j = 0; j < 5; j++) {
              ns[ni][rg][j].x += g * stv[j].x;
              ns[ni][rg][j].y += g * stv[j].y;
            }
          }
      }
    }

    __syncthreads();                       // all waves done reading Ash
    if (k < 5)                             // stage next step's A during the reduce
      stageA(Mt2 + ((size_t)s * 384 + 64 * (k + 1)) * LDA2, Ash, tid);

    // fold a-parity (lane^32), then 4 waves -> 2 LDS regions -> St
#pragma unroll
    for (int ni = 0; ni < 2; ni++)
#pragma unroll
      for (int rg = 0; rg < 4; rg++)
#pragma unroll
        for (int j = 0; j < 5; j++) {
          ns[ni][rg][j].x += __shfl_xor(ns[ni][rg][j].x, 32, 64);
          ns[ni][rg][j].y += __shfl_xor(ns[ni][rg][j].y, 32, 64);
        }

    if (wave < 2 && fq < 2) {
#pragma unroll
      for (int ni = 0; ni < 2; ni++)
#pragma unroll
        for (int rg = 0; rg < 4; rg++)
#pragma unroll
          for (int j = 0; j < 5; j++)
            *(float2*)&NSp[wave][((fql * 4 + rg) * 32 + (ni * 16 + fr)) * 10 + 2 * j] = ns[ni][rg][j];
    }
    __syncthreads();
    if (wave >= 2 && fq < 2) {
#pragma unroll
      for (int ni = 0; ni < 2; ni++)
#pragma unroll
        for (int rg = 0; rg < 4; rg++)
#pragma unroll
          for (int j = 0; j < 5; j++) {
            float2* p = (float2*)&NSp[wave - 2][((fql * 4 + rg) * 32 + (ni * 16 + fr)) * 10 + 2 * j];
            float2 cur = *p;
            cur.x += ns[ni][rg][j].x; cur.y += ns[ni][rg][j].y;
            *p = cur;
          }
    }
    __syncthreads();
    {
      float* d = &St[tid * 12];
      const float* p0 = &NSp[0][tid * 10];
      const float* p1 = &NSp[1][tid * 10];
#pragma unroll
      for (int c = 0; c < 10; c += 2) {
        float2 a = *(const float2*)&p0[c];
        float2 b = *(const float2*)&p1[c];
        a.x += b.x; a.y += b.y;
        *(float2*)&d[c] = a;
      }
    }
  }
  __syncthreads();

  // out[s,c] = sum_{a,l} St[a,l,c] * GN[a][s][l]
  {
    const int a = tid >> 5, l = tid & 31;
    const float gn = GN[((size_t)a * 512 + s) * 32 + l];
    const float* stp = &St[tid * 12];
#pragma unroll
    for (int c = 0; c < 10; c++) {
      float v = gn * stp[c];
#pragma unroll
      for (int o2 = 1; o2 < 64; o2 <<= 1) v += __shfl_xor(v, o2, 64);
      if (lane == 0) atomicAdd(&oc[c], v);
    }
    __syncthreads();
    if (tid < 10) out[(size_t)s * 10 + tid] = oc[tid];
  }
}

// ---------------- prep kernels ----------------
__global__ void prep_xh(const float* __restrict__ x, _Float16* __restrict__ xh) {
  const int idx = blockIdx.x * 256 + threadIdx.x;
  const int q = idx & 63, sp = idx >> 6;
  xh[idx] = (q < 48) ? (_Float16)x[sp * 48 + q] : (_Float16)0.f;
}

__global__ void prep_ckt(const float* __restrict__ cf, const float* __restrict__ cm,
                         const float* __restrict__ cl, _Float16* __restrict__ Ckt) {
  const int idx = blockIdx.x * 256 + threadIdx.x;
  const int q = idx & 63;
  const int row = idx >> 6;
  float v = 0.f;
  if (q < 48) {
    if (row < 8) v = cf[q * 8 + row];
    else if (row < 392) {
      const int rr = row - 8;
      const int k = rr >> 6, ab = rr & 63, a = ab >> 3, b = ab & 7;
      v = cm[((k * 8 + a) * 48 + q) * 8 + b];
    } else if (row < 400) v = cl[(row - 392) * 48 + q];
  }
  Ckt[idx] = (_Float16)v;
}

__global__ void prep_akr(const float* __restrict__ tm, _Float16* __restrict__ Akr) {
  const int idx = blockIdx.x * 256 + threadIdx.x;
  const int p = idx % 224;
  const int lr = (idx / 224) & 1023;
  const int k = idx / (224 * 1024);
  const int l = lr >> 5, r = lr & 31;
  float v = 0.f;
  if (p < 196) v = tm[(((k * 32 + l) * 196) + p) * 32 + r];
  Akr[idx] = (_Float16)v;
}

__global__ void prep_bt0(const float* __restrict__ tf, _Float16* __restrict__ Bt0) {
  const int idx = blockIdx.x * 256 + threadIdx.x;
  const int p = idx % 224;
  const int n = idx / 224;
  float v = 0.f;
  if (n < 320 && p < 196) {
    const int r = n / 10, c = n % 10;
    v = tf[(c * 196 + p) * 32 + r];
  }
  Bt0[idx] = (_Float16)v;
}

__global__ void prep_btl(const float* __restrict__ tl, _Float16* __restrict__ Btl) {
  const int idx = blockIdx.x * 256 + threadIdx.x;
  const int p = idx % 224;
  const int n = idx / 224;
  float v = 0.f;
  if (n < 32 && p < 196) v = tl[n * 196 + p];
  Btl[idx] = (_Float16)v;
}

// zero all K-pad bytes: Mt2 rows (196..232) + MtF/MtL rows (196..224)
__global__ void zero_pads(_Float16* __restrict__ Mt2, _Float16* __restrict__ MtF,
                          _Float16* __restrict__ MtL) {
  const int idx = blockIdx.x * 256 + threadIdx.x;   // 196608 threads
  if (idx < 196608) {
    _Float16* p = Mt2 + (size_t)idx * LDA2 + 196;
#pragma unroll
    for (int j = 0; j < 36; j++) p[j] = (_Float16)0.f;
  }
  if (idx < 4096) {
    _Float16* p = MtF + (size_t)idx * KP + 196;
    _Float16* q = MtL + (size_t)idx * KP + 196;
#pragma unroll
    for (int j = 0; j < 28; j++) { p[j] = (_Float16)0.f; q[j] = (_Float16)0.f; }
  }
}

extern "C" void kernel_launch(void* const* d_in, const int* in_sizes, int n_in,
                              void* d_out, int out_size, void* d_ws, size_t ws_size,
                              hipStream_t stream)
{
  const float* x  = (const float*)d_in[0];
  const float* cf = (const float*)d_in[1];
  const float* cm = (const float*)d_in[2];
  const float* cl = (const float*)d_in[3];
  const float* tf = (const float*)d_in[4];
  const float* tm = (const float*)d_in[5];
  const float* tl = (const float*)d_in[6];
  float* out = (float*)d_out;

  char* w = (char*)d_ws;
  auto alloc = [&](size_t bytes) { char* p = w; w += (bytes + 255) & ~(size_t)255; return p; };
  _Float16* xh  = (_Float16*)alloc(100352ull * 64 * 2);        // 12.8 MB
  _Float16* Ckt = (_Float16*)alloc(512ull * 64 * 2);
  _Float16* Mt2 = (_Float16*)alloc(512ull * 384 * LDA2 * 2);   // 91.2 MB  [s][row][232]
  _Float16* MtF = (_Float16*)alloc(8ull * 512 * KP * 2);       // 1.8 MB   [b][s][224]
  _Float16* MtL = (_Float16*)alloc(8ull * 512 * KP * 2);       // 1.8 MB   [a][s][224]
  _Float16* Akr = (_Float16*)alloc(6ull * 1024 * KP * 2);      // 2.75 MB
  _Float16* Bt0 = (_Float16*)alloc(384ull * KP * 2);
  _Float16* Btl = (_Float16*)alloc(128ull * KP * 2);
  float* stA    = (float*)alloc(512ull * 2560 * 4);            // 5.2 MB
  float* GN     = (float*)alloc(4096ull * 32 * 4);
  (void)ws_size; (void)in_sizes; (void)n_in; (void)out_size;

  prep_xh <<<25088, 256, 0, stream>>>(x, xh);
  prep_ckt<<<  128, 256, 0, stream>>>(cf, cm, cl, Ckt);
  prep_akr<<< 5376, 256, 0, stream>>>(tm, Akr);
  prep_bt0<<<  336, 256, 0, stream>>>(tf, Bt0);
  prep_btl<<<  112, 256, 0, stream>>>(tl, Btl);
  zero_pads<<<  768, 256, 0, stream>>>(Mt2, MtF, MtL);

  gemm_mfma<QP, 0><<<dim3(784, 4), 256, 0, stream>>>(Ckt, xh, Mt2, MtF, MtL);
  gemm_mfma<KP, 2><<<dim3(3, 32), 256, 0, stream>>>(MtF, Bt0, stA, nullptr, nullptr);
  gemm_mfma<KP, 3><<<dim3(1, 32), 256, 0, stream>>>(MtL, Btl, GN, nullptr, nullptr);

  chain_kernel<<<512, 256, 0, stream>>>(Mt2, Akr, stA, GN, out);
}

// Round 4
// 271.490 us; speedup vs baseline: 1.5716x; 1.5716x over previous
//
#include <hip/hip_runtime.h>

// TensorConvolutionTrainLayer: S=512,P=196,Q=48,CB=8,R=32,C=10,N=8
// R4: chain state-update is MFMA too (kills the 80-reg VALU accumulator that was
// spilling 139 MB/dispatch to scratch in R2/R3).
//   Per step, per cc chunk (128 lr cols = l in {4cc..4cc+3}):
//     G-MFMA (64 ab x 128 lr, K=224) -> accs
//     cvt f16, ds_write_b64 into Gsh[cc&1] as [m=(b,r)=256][k'=(l-4cc)*8+sigma(a)=32]
//     barrier; NS[m][c] += mfma(Gsh row m, St3 row c, k-window cc*32..+32)
//   St3[c][l*8+sigma(a)] f16 doubles as state storage AND next B-operand.
//   sigma(a)=(a&1)*4+(a>>1) makes each lane's 4 mi-values k'-contiguous (b64 packs).

typedef _Float16 half8 __attribute__((ext_vector_type(8)));
typedef _Float16 half4 __attribute__((ext_vector_type(4)));
typedef float floatx4 __attribute__((ext_vector_type(4)));

#define KP 224    // P padded to 7*32
#define QP 64     // Q padded to 2*32
#define LDA2 232  // Mt2 row stride (halfs) = 29 x 16B chunks
#define GSTR 40   // Gsh row stride (halfs): 80B, 16B-aligned, stride-20-dword banks
#define SSTR 264  // St3 row stride (halfs): 528B, 16B-aligned

__device__ __forceinline__ void gld_lds16(const void* g, void* l) {
  __builtin_amdgcn_global_load_lds((const __attribute__((address_space(1))) void*)g,
                                   (__attribute__((address_space(3))) void*)l, 16, 0, 0);
}

// ---------------- generic MFMA GEMM (unchanged from R3) ----------------
template<int K, int MODE>
__global__ __launch_bounds__(256)
void gemm_mfma(const _Float16* __restrict__ A, const _Float16* __restrict__ Bt,
               void* __restrict__ out0, void* __restrict__ out1, void* __restrict__ out2)
{
  __shared__ __align__(16) _Float16 Ash[128 * 32];
  __shared__ __align__(16) _Float16 Bsh[128 * 32];
  const int tid  = threadIdx.x;
  const int wave = tid >> 6;
  const int lane = tid & 63;
  const int m0 = blockIdx.y * 128;
  const int n0 = blockIdx.x * 128;
  const int wm = (wave >> 1) * 64;
  const int wn = (wave & 1) * 64;
  const int fr = lane & 15;
  const int fq = lane >> 4;

  floatx4 acc[4][4] = {};

  for (int kt = 0; kt < K; kt += 32) {
    __syncthreads();
#pragma unroll
    for (int j = 0; j < 2; j++) {
      const int c   = j * 256 + tid;
      const int row = c >> 2;
      const int ko  = (c & 3) * 8;
      gld_lds16(A  + (size_t)(m0 + row) * K + kt + ko,
                (char*)Ash + (size_t)(j * 256 + wave * 64) * 16);
      gld_lds16(Bt + (size_t)(n0 + row) * K + kt + ko,
                (char*)Bsh + (size_t)(j * 256 + wave * 64) * 16);
    }
    __syncthreads();
    half8 af[4], bf[4];
#pragma unroll
    for (int i = 0; i < 4; i++)
      af[i] = *(const half8*)&Ash[(wm + i * 16 + fr) * 32 + fq * 8];
#pragma unroll
    for (int i = 0; i < 4; i++)
      bf[i] = *(const half8*)&Bsh[(wn + i * 16 + fr) * 32 + fq * 8];
#pragma unroll
    for (int i = 0; i < 4; i++)
#pragma unroll
      for (int j = 0; j < 4; j++)
        acc[i][j] = __builtin_amdgcn_mfma_f32_16x16x32_f16(af[i], bf[j], acc[i][j], 0, 0, 0);
  }

#pragma unroll
  for (int i = 0; i < 4; i++) {
#pragma unroll
    for (int j = 0; j < 4; j++) {
#pragma unroll
      for (int r = 0; r < 4; r++) {
        const int m = m0 + wm + i * 16 + fq * 4 + r;
        const int n = n0 + wn + j * 16 + fr;
        const float v = acc[i][j][r];
        if constexpr (MODE == 0) {
          const unsigned s = (unsigned)n / 196u;
          const unsigned p = (unsigned)n - s * 196u;
          if (m < 8)
            ((_Float16*)out1)[((size_t)m * 512 + s) * KP + p] = (_Float16)v;
          else if (m < 392)
            ((_Float16*)out0)[((size_t)s * 384 + (m - 8)) * LDA2 + p] = (_Float16)v;
          else if (m < 400)
            ((_Float16*)out2)[((size_t)(m - 392) * 512 + s) * KP + p] = (_Float16)v;
        } else if constexpr (MODE == 2) {
          if (n < 320)
            ((float*)out0)[(size_t)(m & 511) * 2560 + (m >> 9) * 320 + n] = v;
        } else {
          if (n < 32)
            ((float*)out0)[(size_t)m * 32 + n] = v;
        }
      }
    }
  }
}

// ---------------- fused chain kernel ----------------
__device__ __forceinline__ void stageA(const _Float16* __restrict__ base,
                                       _Float16* __restrict__ ash, int tid) {
  const int wave = tid >> 6;
#pragma unroll
  for (int it = 0; it < 7; it++) {
    const int c = it * 256 + tid;
    gld_lds16(base + (size_t)c * 8, (char*)ash + (size_t)(it * 256 + wave * 64) * 16);
  }
  if (tid < 64)
    gld_lds16(base + (size_t)(1792 + tid) * 8, (char*)ash + (size_t)1792 * 16);
}

__global__ __launch_bounds__(256, 2)
void chain_kernel(const _Float16* __restrict__ Mt2, const _Float16* __restrict__ Akr,
                  const float* __restrict__ St0, const float* __restrict__ GN,
                  float* __restrict__ out)
{
  __shared__ __align__(16) _Float16 Ash[64 * LDA2];        // 29696 B
  __shared__ __align__(16) _Float16 Gsh[2][256 * GSTR];    // 40960 B
  __shared__ __align__(16) _Float16 St3[16 * SSTR];        // 8448 B
  __shared__ float oc[10];

  const int tid  = threadIdx.x;
  const int wave = tid >> 6;
  const int lane = tid & 63;
  const int s    = blockIdx.x;
  const int fr   = lane & 15;
  const int fq   = lane >> 4;
  const int fqh  = fq >> 1;
  const int fql  = fq & 1;

  // init: St3[c][r*8+sigma(b)] from St0[s][b*320+r*10+c]; tid=(b,r)
  {
    const int b = tid >> 5, r = tid & 31;
    const int kcol = r * 8 + ((b & 1) * 4 + (b >> 1));
    const float* src = St0 + (size_t)s * 2560 + (size_t)tid * 10;
#pragma unroll
    for (int c = 0; c < 10; c++) St3[c * SSTR + kcol] = (_Float16)src[c];
    if (tid < 10) oc[tid] = 0.f;
  }
  stageA(Mt2 + (size_t)s * 384 * LDA2, Ash, tid);
  __syncthreads();   // Ash + St3 ready (compiler drains vmcnt before barrier)

  // preload B fragments for (k=0, cc=0)
  half8 bf[7][2];
  {
    const _Float16* Bb = Akr + (size_t)(wave * 32) * KP;
#pragma unroll
    for (int kt = 0; kt < 7; kt++)
#pragma unroll
      for (int ni = 0; ni < 2; ni++)
        bf[kt][ni] = *(const half8*)(Bb + (size_t)(ni * 16 + fr) * KP + kt * 32 + fq * 8);
  }

  for (int k = 0; k < 6; k++) {
    floatx4 ns[4] = {};   // NS accumulators: 4 m-tiles per wave, K reduced in-MFMA

    for (int cc = 0; cc < 8; cc++) {
      // ---- G-phase: G tile [ab 64][lr 128], this wave's 64x32 slice ----
      floatx4 acc[4][2] = {};
#pragma unroll
      for (int kt = 0; kt < 7; kt++) {
        half8 af[4];
#pragma unroll
        for (int mi = 0; mi < 4; mi++)
          af[mi] = *(const half8*)&Ash[(mi * 16 + fr) * LDA2 + kt * 32 + fq * 8];
#pragma unroll
        for (int mi = 0; mi < 4; mi++)
#pragma unroll
          for (int ni = 0; ni < 2; ni++)
            acc[mi][ni] = __builtin_amdgcn_mfma_f32_16x16x32_f16(af[mi], bf[kt][ni], acc[mi][ni], 0, 0, 0);
      }
      // cvt: pack 4 mi-values (k'-contiguous under sigma) per (ni,rg)
      half4 gh[2][4];
#pragma unroll
      for (int ni = 0; ni < 2; ni++)
#pragma unroll
        for (int rg = 0; rg < 4; rg++)
#pragma unroll
          for (int mi = 0; mi < 4; mi++)
            gh[ni][rg][mi] = (_Float16)acc[mi][ni][rg];
      // prefetch next B fragments (consumed after write+barrier+NS ~ covers L2 latency)
      {
        int ncc = cc + 1, nk = k;
        if (ncc == 8) { ncc = 0; nk = k + 1; }
        if (nk < 6) {
          const _Float16* Bn = Akr + ((size_t)nk * 1024 + ncc * 128 + wave * 32) * KP;
#pragma unroll
          for (int kt = 0; kt < 7; kt++)
#pragma unroll
            for (int ni = 0; ni < 2; ni++)
              bf[kt][ni] = *(const half8*)(Bn + (size_t)(ni * 16 + fr) * KP + kt * 32 + fq * 8);
        }
      }
      // write Gsh[cc&1]: row m=(b,r), k' = wave*8 + fqh*4 + mi (b64 packs)
      {
        _Float16* gb = &Gsh[cc & 1][0];
#pragma unroll
        for (int ni = 0; ni < 2; ni++)
#pragma unroll
          for (int rg = 0; rg < 4; rg++) {
            const int m = (fql * 4 + rg) * 32 + ni * 16 + fr;
            *(half4*)&gb[m * GSTR + wave * 8 + fqh * 4] = gh[ni][rg];
          }
      }
      __syncthreads();   // Gsh[cc&1] visible to all waves
      if (cc == 7 && k < 5)   // all waves past their G-phase(7): safe to restage Ash
        stageA(Mt2 + ((size_t)s * 384 + 64 * (k + 1)) * LDA2, Ash, tid);
      // ---- NS-phase: NS[m][c] += G[m][k-slice] * St3[c][k-slice] ----
      {
        const _Float16* gb = &Gsh[cc & 1][0];
        const half8 bs = *(const half8*)&St3[fr * SSTR + cc * 32 + fq * 8];
#pragma unroll
        for (int t = 0; t < 4; t++) {
          const half8 aa = *(const half8*)&gb[((wave * 4 + t) * 16 + fr) * GSTR + fq * 8];
          ns[t] = __builtin_amdgcn_mfma_f32_16x16x32_f16(aa, bs, ns[t], 0, 0, 0);
        }
      }
    }

    __syncthreads();   // all NS reads of St3 done before overwrite
    // epilogue: NS -> St3 (next step's state / B operand). m=(b,r): k_next = r*8+sigma(b)
    if (fr < 10) {
#pragma unroll
      for (int t = 0; t < 4; t++) {
#pragma unroll
        for (int rg = 0; rg < 4; rg++) {
          const int m = (wave * 4 + t) * 16 + fq * 4 + rg;
          const int b = m >> 5, r = m & 31;
          St3[fr * SSTR + r * 8 + ((b & 1) * 4 + (b >> 1))] = (_Float16)ns[t][rg];
        }
      }
    }
    // next iteration's cc=0 barrier orders these writes before any NS read
  }
  __syncthreads();

  // final: out[s,c] = sum_{a,l} St3[c][l*8+sigma(a)] * GN[a][s][l]
  {
    const int a = tid >> 5, l = tid & 31;
    const float gn = GN[((size_t)a * 512 + s) * 32 + l];
    const int kcol = l * 8 + ((a & 1) * 4 + (a >> 1));
#pragma unroll
    for (int c = 0; c < 10; c++) {
      float v = gn * (float)St3[c * SSTR + kcol];
#pragma unroll
      for (int o2 = 1; o2 < 64; o2 <<= 1) v += __shfl_xor(v, o2, 64);
      if (lane == 0) atomicAdd(&oc[c], v);
    }
    __syncthreads();
    if (tid < 10) out[(size_t)s * 10 + tid] = oc[tid];
  }
}

// ---------------- prep kernels (unchanged) ----------------
__global__ void prep_xh(const float* __restrict__ x, _Float16* __restrict__ xh) {
  const int idx = blockIdx.x * 256 + threadIdx.x;
  const int q = idx & 63, sp = idx >> 6;
  xh[idx] = (q < 48) ? (_Float16)x[sp * 48 + q] : (_Float16)0.f;
}

__global__ void prep_ckt(const float* __restrict__ cf, const float* __restrict__ cm,
                         const float* __restrict__ cl, _Float16* __restrict__ Ckt) {
  const int idx = blockIdx.x * 256 + threadIdx.x;
  const int q = idx & 63;
  const int row = idx >> 6;
  float v = 0.f;
  if (q < 48) {
    if (row < 8) v = cf[q * 8 + row];
    else if (row < 392) {
      const int rr = row - 8;
      const int k = rr >> 6, ab = rr & 63, a = ab >> 3, b = ab & 7;
      v = cm[((k * 8 + a) * 48 + q) * 8 + b];
    } else if (row < 400) v = cl[(row - 392) * 48 + q];
  }
  Ckt[idx] = (_Float16)v;
}

__global__ void prep_akr(const float* __restrict__ tm, _Float16* __restrict__ Akr) {
  const int idx = blockIdx.x * 256 + threadIdx.x;
  const int p = idx % 224;
  const int lr = (idx / 224) & 1023;
  const int k = idx / (224 * 1024);
  const int l = lr >> 5, r = lr & 31;
  float v = 0.f;
  if (p < 196) v = tm[(((k * 32 + l) * 196) + p) * 32 + r];
  Akr[idx] = (_Float16)v;
}

__global__ void prep_bt0(const float* __restrict__ tf, _Float16* __restrict__ Bt0) {
  const int idx = blockIdx.x * 256 + threadIdx.x;
  const int p = idx % 224;
  const int n = idx / 224;
  float v = 0.f;
  if (n < 320 && p < 196) {
    const int r = n / 10, c = n % 10;
    v = tf[(c * 196 + p) * 32 + r];
  }
  Bt0[idx] = (_Float16)v;
}

__global__ void prep_btl(const float* __restrict__ tl, _Float16* __restrict__ Btl) {
  const int idx = blockIdx.x * 256 + threadIdx.x;
  const int p = idx % 224;
  const int n = idx / 224;
  float v = 0.f;
  if (n < 32 && p < 196) v = tl[n * 196 + p];
  Btl[idx] = (_Float16)v;
}

__global__ void zero_pads(_Float16* __restrict__ Mt2, _Float16* __restrict__ MtF,
                          _Float16* __restrict__ MtL) {
  const int idx = blockIdx.x * 256 + threadIdx.x;
  if (idx < 196608) {
    _Float16* p = Mt2 + (size_t)idx * LDA2 + 196;
#pragma unroll
    for (int j = 0; j < 36; j++) p[j] = (_Float16)0.f;
  }
  if (idx < 4096) {
    _Float16* p = MtF + (size_t)idx * KP + 196;
    _Float16* q = MtL + (size_t)idx * KP + 196;
#pragma unroll
    for (int j = 0; j < 28; j++) { p[j] = (_Float16)0.f; q[j] = (_Float16)0.f; }
  }
}

extern "C" void kernel_launch(void* const* d_in, const int* in_sizes, int n_in,
                              void* d_out, int out_size, void* d_ws, size_t ws_size,
                              hipStream_t stream)
{
  const float* x  = (const float*)d_in[0];
  const float* cf = (const float*)d_in[1];
  const float* cm = (const float*)d_in[2];
  const float* cl = (const float*)d_in[3];
  const float* tf = (const float*)d_in[4];
  const float* tm = (const float*)d_in[5];
  const float* tl = (const float*)d_in[6];
  float* out = (float*)d_out;

  char* w = (char*)d_ws;
  auto alloc = [&](size_t bytes) { char* p = w; w += (bytes + 255) & ~(size_t)255; return p; };
  _Float16* xh  = (_Float16*)alloc(100352ull * 64 * 2);
  _Float16* Ckt = (_Float16*)alloc(512ull * 64 * 2);
  _Float16* Mt2 = (_Float16*)alloc(512ull * 384 * LDA2 * 2);
  _Float16* MtF = (_Float16*)alloc(8ull * 512 * KP * 2);
  _Float16* MtL = (_Float16*)alloc(8ull * 512 * KP * 2);
  _Float16* Akr = (_Float16*)alloc(6ull * 1024 * KP * 2);
  _Float16* Bt0 = (_Float16*)alloc(384ull * KP * 2);
  _Float16* Btl = (_Float16*)alloc(128ull * KP * 2);
  float* stA    = (float*)alloc(512ull * 2560 * 4);
  float* GN     = (float*)alloc(4096ull * 32 * 4);
  (void)ws_size; (void)in_sizes; (void)n_in; (void)out_size;

  prep_xh <<<25088, 256, 0, stream>>>(x, xh);
  prep_ckt<<<  128, 256, 0, stream>>>(cf, cm, cl, Ckt);
  prep_akr<<< 5376, 256, 0, stream>>>(tm, Akr);
  prep_bt0<<<  336, 256, 0, stream>>>(tf, Bt0);
  prep_btl<<<  112, 256, 0, stream>>>(tl, Btl);
  zero_pads<<<  768, 256, 0, stream>>>(Mt2, MtF, MtL);

  gemm_mfma<QP, 0><<<dim3(784, 4), 256, 0, stream>>>(Ckt, xh, Mt2, MtF, MtL);
  gemm_mfma<KP, 2><<<dim3(3, 32), 256, 0, stream>>>(MtF, Bt0, stA, nullptr, nullptr);
  gemm_mfma<KP, 3><<<dim3(1, 32), 256, 0, stream>>>(MtL, Btl, GN, nullptr, nullptr);

  chain_kernel<<<512, 256, 0, stream>>>(Mt2, Akr, stA, GN, out);
}